// Round 1
// baseline (135.108 us; speedup 1.0000x reference)
//
#include <hip/hip_runtime.h>
#include <math.h>

#define U 8192
#define NITEMS 100000
#define H 50
#define QD 128
#define D 256
#define BMG 8      // rows per block in the thin GEMMs (grid = U/BMG = 1024)
#define NRMAX 13   // max rows per wave in attn: ceil(50/4)

// broadcast block-reduce (256 threads = 4 waves)
__device__ __forceinline__ float block_reduce_256(float v, float* sred) {
    #pragma unroll
    for (int off = 32; off >= 1; off >>= 1)
        v += __shfl_xor(v, off, 64);
    int wave = threadIdx.x >> 6;
    int lane = threadIdx.x & 63;
    if (lane == 0) sred[wave] = v;
    __syncthreads();
    float s;
    if (threadIdx.x == 0) {
        s = sred[0] + sred[1] + sred[2] + sred[3];
        sred[0] = s;
    }
    __syncthreads();
    s = sred[0];
    __syncthreads();
    return s;
}

// Kernel A: M = Wq @ Wk^T [QD,D]; bqt = bq @ Wk^T [D]; wb = Wq @ bk [QD]; c0 = bq.bk
__global__ void __launch_bounds__(256) upa_precompute(
    const float* __restrict__ Wq, const float* __restrict__ bq,
    const float* __restrict__ Wk, const float* __restrict__ bk,
    float* __restrict__ M, float* __restrict__ bqt,
    float* __restrict__ wb, float* __restrict__ c0) {
    __shared__ float row[D];
    __shared__ float sred[4];
    int k = blockIdx.x;
    int t = threadIdx.x;
    if (k < QD) {
        row[t] = (t < D) ? Wq[k * D + t] : 0.f;
        __syncthreads();
        const float4* wkr = (const float4*)(Wk + (size_t)t * D);
        const float4* rr  = (const float4*)row;
        float acc = 0.f;
        #pragma unroll 4
        for (int i = 0; i < D / 4; ++i) {
            float4 a = rr[i]; float4 b = wkr[i];
            acc += a.x * b.x + a.y * b.y + a.z * b.z + a.w * b.w;
        }
        M[k * D + t] = acc;
        float p = row[t] * bk[t];
        float s = block_reduce_256(p, sred);
        if (t == 0) wb[k] = s;
    } else {
        row[t] = bq[t];
        __syncthreads();
        const float4* wkr = (const float4*)(Wk + (size_t)t * D);
        const float4* rr  = (const float4*)row;
        float acc = 0.f;
        #pragma unroll 4
        for (int i = 0; i < D / 4; ++i) {
            float4 a = rr[i]; float4 b = wkr[i];
            acc += a.x * b.x + a.y * b.y + a.z * b.z + a.w * b.w;
        }
        bqt[t] = acc;
        float p = row[t] * bk[t];
        float s = block_reduce_256(p, sred);
        if (t == 0) c0[0] = s;
    }
}

// Kernel B: qt = uq @ M + bqt   [U,D], K=QD. 8 rows/block, K unrolled by 8.
__global__ void __launch_bounds__(256) upa_qt(
    const float* __restrict__ uq, const float* __restrict__ M,
    const float* __restrict__ bqt, float* __restrict__ qt) {
    __shared__ float A[BMG][QD];   // 4 KB
    int u0 = blockIdx.x * BMG;
    int t = threadIdx.x;
    const float4* src = (const float4*)(uq + (size_t)u0 * QD);
    float4* dst = (float4*)&A[0][0];
    for (int i = t; i < BMG * QD / 4; i += 256) dst[i] = src[i];
    __syncthreads();
    float acc[BMG];
    #pragma unroll
    for (int r = 0; r < BMG; ++r) acc[r] = 0.f;
    for (int k8 = 0; k8 < QD; k8 += 8) {
        float m[8];
        #pragma unroll
        for (int i = 0; i < 8; ++i) m[i] = M[(size_t)(k8 + i) * D + t];
        #pragma unroll
        for (int r = 0; r < BMG; ++r) {
            float4 a0 = *((const float4*)&A[r][k8]);
            float4 a1 = *((const float4*)&A[r][k8 + 4]);
            acc[r] += a0.x * m[0] + a0.y * m[1] + a0.z * m[2] + a0.w * m[3]
                    + a1.x * m[4] + a1.y * m[5] + a1.z * m[6] + a1.w * m[7];
        }
    }
    float bb = bqt[t];
    #pragma unroll
    for (int r = 0; r < BMG; ++r) qt[(size_t)(u0 + r) * D + t] = acc[r] + bb;
}

// Kernel C: per-user fused attention, SINGLE-PASS streaming.
// Identity used: w_j = exp(s_j - S)/(sum_k exp(s_k - S) + 1e-12)
//              = exp(s_j) / (sum_k exp(s_k) + 1e-12*exp(S))
// so we accumulate A0 = sum_j exp(s_j)*f_j, E = sum_j exp(s_j), S = sum_j s_j
// in one pass over the gathered rows (each feats row loaded exactly once),
// then normalize at the end:
//   agg[u,:] = A0 / (E + 1e-12*exp(S));  sw[u] = E / (E + 1e-12*exp(S))
__global__ void __launch_bounds__(256, 5) upa_attn(
    const float* __restrict__ qt, const float* __restrict__ uq,
    const float* __restrict__ wb, const float* __restrict__ c0,
    const float* __restrict__ feats, const int* __restrict__ item_idx,
    float* __restrict__ agg, float* __restrict__ sw) {
    __shared__ int   idx_s[H];
    __shared__ float sred[4];
    __shared__ float pagg[4][D];    // 4 KB cross-wave partials
    __shared__ float pE[4], pS[4];
    int u = blockIdx.x;
    int t = threadIdx.x;
    int wave = t >> 6, lane = t & 63;

    if (t < H) idx_s[t] = item_idx[(long long)u * H + t];
    float p = (t < QD) ? uq[(size_t)u * QD + t] * wb[t] : 0.f;
    float qb = block_reduce_256(p, sred) + c0[0];   // syncs inside cover idx_s

    // each wave reads the full qt row (64 lanes x float4)
    float4 q = ((const float4*)(qt + (size_t)u * D))[lane];

    // issue all independent gathers, rows -> registers; pin them so the
    // compiler cannot rematerialize the loads later (VGPR=36 in the previous
    // build proved it was re-loading every row from L2 a second time).
    float4 v[NRMAX];
    #pragma unroll
    for (int r = 0; r < NRMAX; ++r) {
        int j = wave + 4 * r;
        if (j < H) {
            v[r] = ((const float4*)(feats + (size_t)idx_s[j] * D))[lane];
            asm volatile("" : "+v"(v[r].x), "+v"(v[r].y), "+v"(v[r].z), "+v"(v[r].w));
        }
    }

    // single pass: score-reduce, exp, and weighted accumulate per row.
    float4 acc = make_float4(0.f, 0.f, 0.f, 0.f);
    float E = 0.f, S = 0.f;   // wave-uniform after the butterfly reduce
    #pragma unroll
    for (int r = 0; r < NRMAX; ++r) {
        int j = wave + 4 * r;
        if (j < H) {
            float part = v[r].x * q.x + v[r].y * q.y + v[r].z * q.z + v[r].w * q.w;
            #pragma unroll
            for (int off = 32; off >= 1; off >>= 1)
                part += __shfl_xor(part, off, 64);
            float s = part + qb;
            float e = __expf(s);
            S += s;
            E += e;
            acc.x += e * v[r].x;
            acc.y += e * v[r].y;
            acc.z += e * v[r].z;
            acc.w += e * v[r].w;
        }
    }

    // cross-wave combine
    ((float4*)pagg[wave])[lane] = acc;
    if (lane == 0) { pE[wave] = E; pS[wave] = S; }
    __syncthreads();
    float Et = pE[0] + pE[1] + pE[2] + pE[3];
    float St = pS[0] + pS[1] + pS[2] + pS[3];
    float inv = 1.f / (Et + 1e-12f * __expf(St));
    agg[(size_t)u * D + t] =
        (pagg[0][t] + pagg[1][t] + pagg[2][t] + pagg[3][t]) * inv;
    if (t == 0) sw[u] = Et * inv;
}

// Kernel D: out = agg @ Wv + bv * sw[u]   [U,D], K=D. 8 rows/block, K unrolled by 8.
__global__ void __launch_bounds__(256) upa_out(
    const float* __restrict__ agg, const float* __restrict__ Wv,
    const float* __restrict__ bv, const float* __restrict__ sw,
    float* __restrict__ out) {
    __shared__ float A[BMG][D];    // 8 KB
    int u0 = blockIdx.x * BMG;
    int t = threadIdx.x;
    const float4* src = (const float4*)(agg + (size_t)u0 * D);
    float4* dst = (float4*)&A[0][0];
    for (int i = t; i < BMG * D / 4; i += 256) dst[i] = src[i];
    __syncthreads();
    float acc[BMG];
    #pragma unroll
    for (int r = 0; r < BMG; ++r) acc[r] = 0.f;
    for (int k8 = 0; k8 < D; k8 += 8) {
        float m[8];
        #pragma unroll
        for (int i = 0; i < 8; ++i) m[i] = Wv[(size_t)(k8 + i) * D + t];
        #pragma unroll
        for (int r = 0; r < BMG; ++r) {
            float4 a0 = *((const float4*)&A[r][k8]);
            float4 a1 = *((const float4*)&A[r][k8 + 4]);
            acc[r] += a0.x * m[0] + a0.y * m[1] + a0.z * m[2] + a0.w * m[3]
                    + a1.x * m[4] + a1.y * m[5] + a1.z * m[6] + a1.w * m[7];
        }
    }
    float b = bv[t];
    #pragma unroll
    for (int r = 0; r < BMG; ++r)
        out[(size_t)(u0 + r) * D + t] = acc[r] + b * sw[u0 + r];
}

extern "C" void kernel_launch(void* const* d_in, const int* in_sizes, int n_in,
                              void* d_out, int out_size, void* d_ws, size_t ws_size,
                              hipStream_t stream) {
    const float* uq    = (const float*)d_in[0];   // [U,QD]
    const float* feats = (const float*)d_in[1];   // [N,D]
    const float* Wq    = (const float*)d_in[2];   // [QD,D]
    const float* bq    = (const float*)d_in[3];   // [D]
    const float* Wk    = (const float*)d_in[4];   // [D,D]
    const float* bk    = (const float*)d_in[5];   // [D]
    const float* Wv    = (const float*)d_in[6];   // [D,D]
    const float* bv    = (const float*)d_in[7];   // [D]
    // d_in[8] = batch_user_indices: structurally repeat(arange(U),H) -> implicit
    const int* item_idx = (const int*)d_in[9];    // [E]
    float* out = (float*)d_out;

    float* ws  = (float*)d_ws;
    float* M   = ws;                    // QD*D   = 32768
    float* bqt = M + QD * D;            // D      = 256
    float* wb  = bqt + D;               // QD     = 128
    float* c0  = wb + QD;               // 4 (padded)
    float* qt  = c0 + 4;                // U*D    = 2097152
    float* agg = qt + (size_t)U * D;    // U*D    = 2097152
    float* sw  = agg + (size_t)U * D;   // U      = 8192

    upa_precompute<<<QD + 1, 256, 0, stream>>>(Wq, bq, Wk, bk, M, bqt, wb, c0);
    upa_qt<<<U / BMG, 256, 0, stream>>>(uq, M, bqt, qt);
    upa_attn<<<U, 256, 0, stream>>>(qt, uq, wb, c0, feats, item_idx, agg, sw);
    upa_out<<<U / BMG, 256, 0, stream>>>(agg, Wv, bv, sw, out);
}